// Round 1
// 2105.549 us; speedup vs baseline: 1.1694x; 1.1694x over previous
//
#include <hip/hip_runtime.h>
#include <stdint.h>

#define BB 16
#define EE 256
#define TT 4096
#define FF 512
#define RK 10
#define NIT 5

typedef short bf16x8 __attribute__((ext_vector_type(8)));
typedef float f32x4  __attribute__((ext_vector_type(4)));

__device__ __forceinline__ unsigned short f2bf(float x){
  unsigned int u = __float_as_uint(x);
  unsigned int r = (u + 0x7FFFu + ((u >> 16) & 1u)) >> 16;
  return (unsigned short)r;
}
__device__ __forceinline__ float bf2f(unsigned short s){
  return __uint_as_float(((unsigned int)s) << 16);
}

// async global->LDS, 16B per lane; LDS dest must be linear in lane order.
__device__ __forceinline__ void gld16(const void* g, void* l){
  __builtin_amdgcn_global_load_lds((const __attribute__((address_space(1))) unsigned int*)g,
                                   (__attribute__((address_space(3))) unsigned int*)l,
                                   16, 0, 0);
}

// ---------------- setup kernels ----------------

__global__ void k_params(const float* lam_log, const float* mu_log,
                         const float* nu_log, const float* gl, float* prm){
  int k = threadIdx.x;
  if (k < NIT){
    float lam = expf(lam_log[k]);
    float mu  = expf(mu_log[k]);
    float nu  = expf(nu_log[k]);
    float gam = 1.0f/(1.0f+expf(-gl[k]));
    prm[k*8+0]=lam; prm[k*8+1]=mu; prm[k*8+2]=nu; prm[k*8+3]=gam; prm[k*8+4]=lam/nu;
  }
}

// X = Om*Y ; also emit Omega as bf16 (binary -> exact)
__global__ void k_initX(const float4* __restrict__ Y, const float4* __restrict__ Om,
                        float4* __restrict__ X, ushort4* __restrict__ Omb){
  int i = blockIdx.x*256 + threadIdx.x;
  float4 y = Y[i], o = Om[i];
  X[i] = make_float4(y.x*o.x, y.y*o.y, y.z*o.z, y.w*o.w);
  ushort4 ob; ob.x=f2bf(o.x); ob.y=f2bf(o.y); ob.z=f2bf(o.z); ob.w=f2bf(o.w);
  Omb[i] = ob;
}

__global__ void k_qtrans(const float* __restrict__ Q0, float* __restrict__ Qt){
  int idx = blockIdx.x*256 + threadIdx.x;   // b*TT + t
  int b = idx >> 12, t = idx & (TT-1);
  #pragma unroll
  for (int j=0;j<RK;j++)
    Qt[((size_t)b*RK + j)*TT + t] = Q0[(size_t)idx*RK + j];
}

__global__ void k_rtrans(const float* __restrict__ Rm, float* __restrict__ Rt){
  int f = blockIdx.x, b = blockIdx.y, e = threadIdx.x;
  Rt[((size_t)b*FF + f)*EE + e] = Rm[((size_t)b*EE + e)*FF + f];
}

// R -> bf16 (binary, exact)
__global__ void k_rbf(const float4* __restrict__ R, ushort4* __restrict__ Rb){
  int i = blockIdx.x*256 + threadIdx.x;
  float4 v = R[i];
  ushort4 o; o.x=f2bf(v.x); o.y=f2bf(v.y); o.z=f2bf(v.z); o.w=f2bf(v.w);
  Rb[i] = o;
}

// A_scale = (R*R)^T @ (Om*Om), stored bf16 (counts <=256 exact)
__global__ void k_ascale(const float* __restrict__ Rt, const unsigned short* __restrict__ Omb,
                         unsigned short* __restrict__ As){
  int id = blockIdx.x;
  int xcd = id & 7;
  int within = id >> 3;            // 0..4095
  int f = within & (FF-1);
  int g = ((within >> 9) << 3) + xcd;  // 0..63
  int b = g >> 2;
  int t = (g & 3)*1024 + threadIdx.x*4;
  __shared__ int s_cnt;
  __shared__ short s_idx[EE];
  __shared__ float s_w[EE];
  if (threadIdx.x==0) s_cnt = 0;
  __syncthreads();
  {
    int e = threadIdx.x;
    float w = Rt[((size_t)b*FF + f)*EE + e];
    if (w != 0.0f){ int p = atomicAdd(&s_cnt,1); s_idx[p]=(short)e; s_w[p]=w*w; }
  }
  __syncthreads();
  int cnt = s_cnt;
  float4 acc = {0,0,0,0};
  const unsigned short* Ob = Omb + (size_t)b*EE*TT + t;
  for (int it=0; it<cnt; ++it){
    int e = s_idx[it]; float w2 = s_w[it];
    ushort4 ou = *(const ushort4*)(Ob + (size_t)e*TT);
    float ox=bf2f(ou.x), oy=bf2f(ou.y), oz=bf2f(ou.z), ow=bf2f(ou.w);
    acc.x += w2*ox*ox; acc.y += w2*oy*oy; acc.z += w2*oz*oz; acc.w += w2*ow*ow;
  }
  ushort4 r; r.x=f2bf(acc.x); r.y=f2bf(acc.y); r.z=f2bf(acc.z); r.w=f2bf(acc.w);
  *(ushort4*)(As + ((size_t)b*FF + f)*TT + t) = r;
}

// ---------------- per-iteration small kernels ----------------

__global__ void k_lhsQ(const float* __restrict__ Qt, const float* __restrict__ prm,
                       float* __restrict__ lhs, int k){
  int p = blockIdx.x, b = blockIdx.y;
  int i = 0, rem = p;
  while (rem >= i+1){ rem -= (i+1); ++i; }
  int j = rem;
  const float* qi = Qt + ((size_t)b*RK + i)*TT;
  const float* qj = Qt + ((size_t)b*RK + j)*TT;
  float a = 0.0f;
  for (int t = threadIdx.x*4; t < TT; t += 1024){
    float4 x = *(const float4*)(qi+t);
    float4 y = *(const float4*)(qj+t);
    a += x.x*y.x + x.y*y.y + x.z*y.z + x.w*y.w;
  }
  __shared__ float red[256];
  red[threadIdx.x] = a; __syncthreads();
  for (int s=128; s>0; s>>=1){
    if (threadIdx.x < s) red[threadIdx.x] += red[threadIdx.x+s];
    __syncthreads();
  }
  if (threadIdx.x==0){
    float v = red[0];
    if (i==j) v += prm[k*8+4];
    lhs[(b*RK+i)*RK + j] = v;
    lhs[(b*RK+j)*RK + i] = v;
  }
}

__global__ void k_lhsP(const float* __restrict__ P, const float* __restrict__ prm,
                       float* __restrict__ lhs, int k){
  int p = blockIdx.x, b = blockIdx.y;
  int i = 0, rem = p;
  while (rem >= i+1){ rem -= (i+1); ++i; }
  int j = rem;
  int e = threadIdx.x;
  const float* pr = P + ((size_t)b*EE + e)*RK;
  float a = pr[i]*pr[j];
  __shared__ float red[256];
  red[threadIdx.x] = a; __syncthreads();
  for (int s=128; s>0; s>>=1){
    if (threadIdx.x < s) red[threadIdx.x] += red[threadIdx.x+s];
    __syncthreads();
  }
  if (threadIdx.x==0){
    float v = red[0];
    if (i==j) v += prm[k*8+4];
    lhs[(b*RK+i)*RK + j] = v;
    lhs[(b*RK+j)*RK + i] = v;
  }
}

__global__ void k_invert(const float* __restrict__ lhs, float* __restrict__ inv){
  int b = blockIdx.x;
  __shared__ float aug[RK][2*RK];
  int tid = threadIdx.x;
  int i = tid / (2*RK), j = tid % (2*RK);
  bool act = tid < RK*2*RK;
  if (act) aug[i][j] = (j < RK) ? lhs[(b*RK+i)*RK + j] : ((j-RK)==i ? 1.0f : 0.0f);
  __syncthreads();
  for (int kk=0; kk<RK; ++kk){
    float pinv = 1.0f / aug[kk][kk];
    __syncthreads();
    if (act && i==kk) aug[i][j] *= pinv;
    __syncthreads();
    float factor = (act && i!=kk) ? aug[i][kk] : 0.0f;
    float pivrow = act ? aug[kk][j] : 0.0f;
    __syncthreads();
    if (act && i!=kk) aug[i][j] -= factor * pivrow;
    __syncthreads();
  }
  if (act && j >= RK) inv[(b*RK+i)*RK + (j-RK)] = aug[i][j];
}

__global__ void k_Pupd(const float* __restrict__ X, const float* __restrict__ Qt,
                       const float* __restrict__ inv, float* __restrict__ P){
  int e = blockIdx.x, b = blockIdx.y;
  const float* xr = X + ((size_t)b*EE + e)*TT;
  const float* qb = Qt + (size_t)b*RK*TT;
  float acc[RK];
  #pragma unroll
  for (int j=0;j<RK;j++) acc[j]=0.0f;
  for (int t = threadIdx.x*4; t < TT; t += 1024){
    float4 x = *(const float4*)(xr+t);
    #pragma unroll
    for (int j=0;j<RK;j++){
      float4 q = *(const float4*)(qb + (size_t)j*TT + t);
      acc[j] += x.x*q.x + x.y*q.y + x.z*q.z + x.w*q.w;
    }
  }
  __shared__ float partial[4][RK];
  int lane = threadIdx.x & 63, wv = threadIdx.x >> 6;
  #pragma unroll
  for (int j=0;j<RK;j++){
    float v = acc[j];
    for (int s=32;s>0;s>>=1) v += __shfl_down(v, s, 64);
    if (lane==0) partial[wv][j] = v;
  }
  __syncthreads();
  if (threadIdx.x < RK){
    int i = threadIdx.x;
    float out = 0.0f;
    #pragma unroll
    for (int j=0;j<RK;j++){
      float xq = partial[0][j]+partial[1][j]+partial[2][j]+partial[3][j];
      out += xq * inv[(b*RK+j)*RK + i];
    }
    P[((size_t)b*EE + e)*RK + i] = out;
  }
}

__global__ void k_Qupd(const float* __restrict__ X, const float* __restrict__ P,
                       const float* __restrict__ inv, float* __restrict__ Qt){
  int b = blockIdx.y;
  int t = blockIdx.x*256 + threadIdx.x;
  __shared__ float sP[EE*RK];
  __shared__ float sInv[RK*RK];
  for (int i=threadIdx.x; i<EE*RK; i+=256) sP[i] = P[(size_t)b*EE*RK + i];
  if (threadIdx.x < RK*RK) sInv[threadIdx.x] = inv[b*RK*RK + threadIdx.x];
  __syncthreads();
  float acc[RK];
  #pragma unroll
  for (int j=0;j<RK;j++) acc[j]=0.0f;
  const float* xb = X + (size_t)b*EE*TT + t;
  for (int e=0;e<EE;e++){
    float x = xb[(size_t)e*TT];
    #pragma unroll
    for (int j=0;j<RK;j++) acc[j] += x * sP[e*RK+j];
  }
  #pragma unroll
  for (int i=0;i<RK;i++){
    float q = 0.0f;
    #pragma unroll
    for (int j=0;j<RK;j++) q += acc[j]*sInv[j*RK+i];
    Qt[((size_t)b*RK + i)*TT + t] = q;
  }
}

// ---------------- A transpose: A fp32 [f][t] -> Abt bf16 [t][f] ----------------
// 64x64 tiles through LDS [64][65]; in: float4 coalesced, out: 128B rows of Abt.
__global__ void k_atrans(const float* __restrict__ A, unsigned short* __restrict__ Abt){
  __shared__ float sT[64][65];
  int b  = blockIdx.z;
  int F0 = blockIdx.y*64, T0 = blockIdx.x*64;
  int tid = threadIdx.x;
  int fi = tid >> 4;          // 0..15
  int m  = tid & 15;
  #pragma unroll
  for (int pass=0; pass<4; ++pass){
    int f = pass*16 + fi;
    float4 v = *(const float4*)(A + ((size_t)(b*FF + F0 + f))*TT + T0 + m*4);
    sT[f][m*4+0]=v.x; sT[f][m*4+1]=v.y; sT[f][m*4+2]=v.z; sT[f][m*4+3]=v.w;
  }
  __syncthreads();
  #pragma unroll
  for (int pass=0; pass<4; ++pass){
    int t  = pass*16 + fi;
    int f4 = m*4;
    ushort4 o;
    o.x = f2bf(sT[f4+0][t]); o.y = f2bf(sT[f4+1][t]);
    o.z = f2bf(sT[f4+2][t]); o.w = f2bf(sT[f4+3][t]);
    *(ushort4*)(Abt + ((size_t)b*TT + T0 + t)*FF + F0 + f4) = o;
  }
}

// ---------------- fused MFMA gemm1: RA = R@A (dense bf16), X update, resid ----------------
// 128x128 output tile per block, K=512 in 16 steps of 32 (one mfma_16x16x32 per step/frag).
// sA = R-tile [128e][32f] bf16, sB = Abt-tile [128t][32f] bf16; both staged via
// global_load_lds (linear LDS) with XOR-slot swizzle applied to the SOURCE address
// and the same XOR on the read side (involution, rule #21). 2-way banks = free.
__global__ __launch_bounds__(256) void k_gemm1m(
    const unsigned short* __restrict__ Rb, const unsigned short* __restrict__ Abt,
    const float* __restrict__ Y, const unsigned short* __restrict__ Omb,
    const float* __restrict__ Qt, const float* __restrict__ P,
    const float* __restrict__ prm, float* __restrict__ X,
    unsigned short* __restrict__ resid, int k)
{
  __shared__ __align__(16) unsigned char lds[16384];
  int id = blockIdx.x;                 // 1024 blocks = b(16) x e-tile(2) x t-tile(32)
  int b  = id >> 6;
  int e0 = ((id >> 5) & 1) * 128;
  int t0 = (id & 31) * 128;
  int tid  = threadIdx.x;
  int lane = tid & 63, wid = tid >> 6;
  int lr = lane & 15, lg = lane >> 4;
  int wm = wid >> 1, wn = wid & 1;     // 2x2 waves, 64x64 out each

  f32x4 acc[4][4];
  #pragma unroll
  for (int m=0;m<4;++m)
    #pragma unroll
    for (int n=0;n<4;++n)
      #pragma unroll
      for (int i=0;i<4;++i) acc[m][n][i]=0.0f;

  if (k > 0){
    // read offsets: row = (w*64 + frag*16 + lr), slot = lg ^ (row&3) = lg ^ (lr&3)
    int swz  = ((lg ^ (lr & 3)) << 4);
    int aoff = (wm*64 + lr)*64 + swz;
    int boff = 8192 + (wn*64 + lr)*64 + swz;
    // staging: 512 chunks of 16B per tile; thread owns chunks tid and tid+256
    int c0 = tid, c1 = tid + 256;
    int r0 = c0 >> 2, s0 = c0 & 3;
    int r1 = c1 >> 2, s1 = c1 & 3;
    const unsigned short* gA0 = Rb  + ((size_t)(b*EE + e0 + r0))*FF + ((s0 ^ (r0&3))<<3);
    const unsigned short* gA1 = Rb  + ((size_t)(b*EE + e0 + r1))*FF + ((s1 ^ (r1&3))<<3);
    const unsigned short* gB0 = Abt + ((size_t)b*TT + t0 + r0)*FF   + ((s0 ^ (r0&3))<<3);
    const unsigned short* gB1 = Abt + ((size_t)b*TT + t0 + r1)*FF   + ((s1 ^ (r1&3))<<3);
    unsigned char* lA0 = lds + c0*16;
    unsigned char* lA1 = lds + c1*16;
    unsigned char* lB0 = lds + 8192 + c0*16;
    unsigned char* lB1 = lds + 8192 + c1*16;

    for (int kk=0; kk<16; ++kk){
      __syncthreads();                     // prev step's ds_reads done
      int f0 = kk*32;
      gld16(gA0 + f0, lA0);
      gld16(gA1 + f0, lA1);
      gld16(gB0 + f0, lB0);
      gld16(gB1 + f0, lB1);
      asm volatile("s_waitcnt vmcnt(0)" ::: "memory");
      __syncthreads();                     // tile visible to all waves
      bf16x8 af[4], bb[4];
      #pragma unroll
      for (int m=0;m<4;++m) af[m] = *(const bf16x8*)(lds + aoff + m*1024);
      #pragma unroll
      for (int n=0;n<4;++n) bb[n] = *(const bf16x8*)(lds + boff + n*1024);
      #pragma unroll
      for (int m=0;m<4;++m)
        #pragma unroll
        for (int n=0;n<4;++n)
          acc[m][n] = __builtin_amdgcn_mfma_f32_16x16x32_bf16(af[m], bb[n], acc[m][n], 0, 0, 0);
    }
  }

  // epilogue: stage P-block [128][RK] and Qt-block [RK][128] fp32 into LDS (reuse)
  __syncthreads();
  float* Pl = (float*)lds;
  float* Ql = (float*)(lds + 8192);
  for (int idx = tid; idx < 128*RK; idx += 256)
    Pl[idx] = P[((size_t)(b*EE + e0))*RK + idx];
  for (int idx = tid; idx < RK*128; idx += 256){
    int j = idx >> 7, t = idx & 127;
    Ql[idx] = Qt[((size_t)(b*RK + j))*TT + t0 + t];
  }
  __syncthreads();

  float nu = prm[k*8+2];
  #pragma unroll
  for (int m=0;m<4;++m){
    #pragma unroll
    for (int r=0;r<4;++r){
      int eloc = wm*64 + m*16 + lg*4 + r;        // C/D row = (lane>>4)*4 + reg
      float pv[RK];
      #pragma unroll
      for (int j=0;j<RK;++j) pv[j] = Pl[eloc*RK + j];
      size_t rowoff = ((size_t)(b*EE + e0 + eloc))*TT + t0;
      #pragma unroll
      for (int n=0;n<4;++n){
        int tloc = wn*64 + n*16 + lr;            // C/D col = lane&15
        float ra = acc[m][n][r];
        float pq = 0.0f;
        #pragma unroll
        for (int j=0;j<RK;++j) pq += pv[j]*Ql[j*128 + tloc];
        size_t off = rowoff + tloc;
        float y = Y[off];
        float o = bf2f(Omb[off]);
        float d = y - ra, om2 = o*o;
        float x = (om2*d + nu*pq)/(om2 + nu);
        float rs = o*(y - x - ra);
        X[off] = x;
        resid[off] = f2bf(rs);
      }
    }
  }
}

__device__ __forceinline__ float aupd(float a, float g, unsigned short asu,
                                      float mu, float gamma){
  float as = bf2f(asu);
  bool no = (as == 0.0f);
  float rs = 1.0f / (no ? 1.0f : as);
  float ba = a + g*rs;
  float ad = copysignf(fmaxf(fabsf(ba) - mu*rs, 0.0f), ba);
  if (no) ad = 0.0f;
  return a + gamma*(ad - a);
}

// G = R^T@resid (sparse row-sum), fused A soft-threshold update; 1D grid 32768, XCD-swizzled
__global__ void k_gemm2(const float* __restrict__ Rt, const unsigned short* __restrict__ resid,
                        const unsigned short* __restrict__ As,
                        const float* __restrict__ prm, float* __restrict__ A, int k){
  int id = blockIdx.x;
  int xcd = id & 7;
  int within = id >> 3;                 // 0..4095
  int f = within & (FF-1);
  int g = ((within >> 9) << 3) + xcd;   // group 0..63
  int b = g >> 2;
  int t = (g & 3)*1024 + threadIdx.x*4;
  __shared__ int s_cnt;
  __shared__ short s_idx[EE];
  __shared__ float s_w[EE];
  if (threadIdx.x==0) s_cnt = 0;
  __syncthreads();
  {
    int e = threadIdx.x;
    float w = Rt[((size_t)b*FF + f)*EE + e];
    if (w != 0.0f){ int p = atomicAdd(&s_cnt,1); s_idx[p]=(short)e; s_w[p]=w; }
  }
  __syncthreads();
  int cnt = s_cnt;
  float4 gacc = {0,0,0,0};
  const unsigned short* rb = resid + (size_t)b*EE*TT + t;
  for (int it=0; it<cnt; ++it){
    int e = s_idx[it]; float w = s_w[it];
    ushort4 r4 = *(const ushort4*)(rb + (size_t)e*TT);
    gacc.x += w*bf2f(r4.x); gacc.y += w*bf2f(r4.y);
    gacc.z += w*bf2f(r4.z); gacc.w += w*bf2f(r4.w);
  }
  float mu = prm[k*8+1], gamma = prm[k*8+3];
  size_t off = ((size_t)b*FF + f)*TT + t;
  ushort4 asv = *(const ushort4*)(As + off);
  float4 a = *(float4*)(A + off);
  float4 an;
  an.x = aupd(a.x, gacc.x, asv.x, mu, gamma);
  an.y = aupd(a.y, gacc.y, asv.y, mu, gamma);
  an.z = aupd(a.z, gacc.z, asv.z, mu, gamma);
  an.w = aupd(a.w, gacc.w, asv.w, mu, gamma);
  *(float4*)(A + off) = an;
}

// ---------------- launch ----------------

extern "C" void kernel_launch(void* const* d_in, const int* in_sizes, int n_in,
                              void* d_out, int out_size, void* d_ws, size_t ws_size,
                              hipStream_t stream){
  const float* Y   = (const float*)d_in[0];
  const float* Rm  = (const float*)d_in[1];
  const float* Om  = (const float*)d_in[2];
  const float* P0  = (const float*)d_in[3];
  const float* Q0  = (const float*)d_in[4];
  const float* lam = (const float*)d_in[5];
  const float* mu  = (const float*)d_in[6];
  const float* nu  = (const float*)d_in[7];
  const float* gl  = (const float*)d_in[8];
  float* A = (float*)d_out;

  char* ws = (char*)d_ws;
  const size_t X_OFF   = 0;
  const size_t RES_OFF = X_OFF   + (size_t)BB*EE*TT*4;   // X: 64 MiB
  const size_t OMB_OFF = RES_OFF + (size_t)BB*EE*TT*2;   // resid bf16: 32 MiB
  const size_t AS_OFF  = OMB_OFF + (size_t)BB*EE*TT*2;   // Omb bf16: 32 MiB
  const size_t RT_OFF  = AS_OFF  + (size_t)BB*FF*TT*2;   // As bf16: 64 MiB
  const size_t QT_OFF  = RT_OFF  + (size_t)BB*FF*EE*4;   // Rt: 8 MiB
  const size_t P_OFF   = QT_OFF  + (size_t)BB*RK*TT*4;
  const size_t LHS_OFF = P_OFF   + (size_t)BB*EE*RK*4;
  const size_t INV_OFF = LHS_OFF + (size_t)BB*RK*RK*4;
  const size_t PRM_OFF = INV_OFF + (size_t)BB*RK*RK*4;
  const size_t RB_OFF  = PRM_OFF + 4096;                 // R bf16: 4 MiB
  const size_t ABT_OFF = RB_OFF  + (size_t)BB*EE*FF*2;   // Abt bf16: 64 MiB

  float* X    = (float*)(ws + X_OFF);
  unsigned short* resid = (unsigned short*)(ws + RES_OFF);
  unsigned short* Omb   = (unsigned short*)(ws + OMB_OFF);
  unsigned short* As    = (unsigned short*)(ws + AS_OFF);
  float* Rt   = (float*)(ws + RT_OFF);
  float* Qt   = (float*)(ws + QT_OFF);
  float* P    = (float*)(ws + P_OFF);
  float* lhs  = (float*)(ws + LHS_OFF);
  float* inv  = (float*)(ws + INV_OFF);
  float* prm  = (float*)(ws + PRM_OFF);
  unsigned short* Rb  = (unsigned short*)(ws + RB_OFF);
  unsigned short* Abt = (unsigned short*)(ws + ABT_OFF);

  (void)P0; (void)Om; (void)in_sizes; (void)n_in; (void)ws_size;

  hipMemsetAsync(d_out, 0, (size_t)out_size*sizeof(float), stream);
  k_params<<<1, 64, 0, stream>>>(lam, mu, nu, gl, prm);
  k_initX<<<BB*EE*TT/4/256, 256, 0, stream>>>((const float4*)Y, (const float4*)Om,
                                              (float4*)X, (ushort4*)Omb);
  k_qtrans<<<BB*TT/256, 256, 0, stream>>>(Q0, Qt);
  k_rtrans<<<dim3(FF, BB), 256, 0, stream>>>(Rm, Rt);
  k_rbf<<<BB*EE*FF/4/256, 256, 0, stream>>>((const float4*)Rm, (ushort4*)Rb);
  k_ascale<<<FF*4*BB, 256, 0, stream>>>(Rt, Omb, As);

  for (int k=0; k<NIT; ++k){
    k_lhsQ  <<<dim3(55, BB), 256, 0, stream>>>(Qt, prm, lhs, k);
    k_invert<<<BB, 256, 0, stream>>>(lhs, inv);
    k_Pupd  <<<dim3(EE, BB), 256, 0, stream>>>(X, Qt, inv, P);
    k_lhsP  <<<dim3(55, BB), 256, 0, stream>>>(P, prm, lhs, k);
    k_invert<<<BB, 256, 0, stream>>>(lhs, inv);
    k_Qupd  <<<dim3(TT/256, BB), 256, 0, stream>>>(X, P, inv, Qt);
    if (k > 0)
      k_atrans<<<dim3(TT/64, FF/64, BB), 256, 0, stream>>>(A, Abt);
    k_gemm1m<<<BB*2*32, 256, 0, stream>>>(Rb, Abt, Y, Omb, Qt, P, prm, X, resid, k);
    k_gemm2 <<<FF*4*BB, 256, 0, stream>>>(Rt, resid, As, prm, A, k);
  }
}

// Round 2
// 1993.464 us; speedup vs baseline: 1.2351x; 1.0562x over previous
//
#include <hip/hip_runtime.h>
#include <stdint.h>

#define BB 16
#define EE 256
#define TT 4096
#define FF 512
#define RK 10
#define NIT 5

typedef short bf16x8 __attribute__((ext_vector_type(8)));
typedef float f32x4  __attribute__((ext_vector_type(4)));

__device__ __forceinline__ unsigned short f2bf(float x){
  unsigned int u = __float_as_uint(x);
  unsigned int r = (u + 0x7FFFu + ((u >> 16) & 1u)) >> 16;
  return (unsigned short)r;
}
__device__ __forceinline__ float bf2f(unsigned short s){
  return __uint_as_float(((unsigned int)s) << 16);
}

// async global->LDS, 16B per lane; LDS dest linear in lane order.
__device__ __forceinline__ void gld16(const void* g, void* l){
  __builtin_amdgcn_global_load_lds((const __attribute__((address_space(1))) unsigned int*)g,
                                   (__attribute__((address_space(3))) unsigned int*)l,
                                   16, 0, 0);
}

// ---------------- setup kernels ----------------

__global__ void k_params(const float* lam_log, const float* mu_log,
                         const float* nu_log, const float* gl, float* prm){
  int k = threadIdx.x;
  if (k < NIT){
    float lam = expf(lam_log[k]);
    float mu  = expf(mu_log[k]);
    float nu  = expf(nu_log[k]);
    float gam = 1.0f/(1.0f+expf(-gl[k]));
    prm[k*8+0]=lam; prm[k*8+1]=mu; prm[k*8+2]=nu; prm[k*8+3]=gam; prm[k*8+4]=lam/nu;
  }
}

// X = Om*Y ; also emit Omega as bf16 (binary -> exact)
__global__ void k_initX(const float4* __restrict__ Y, const float4* __restrict__ Om,
                        float4* __restrict__ X, ushort4* __restrict__ Omb){
  int i = blockIdx.x*256 + threadIdx.x;
  float4 y = Y[i], o = Om[i];
  X[i] = make_float4(y.x*o.x, y.y*o.y, y.z*o.z, y.w*o.w);
  ushort4 ob; ob.x=f2bf(o.x); ob.y=f2bf(o.y); ob.z=f2bf(o.z); ob.w=f2bf(o.w);
  Omb[i] = ob;
}

__global__ void k_qtrans(const float* __restrict__ Q0, float* __restrict__ Qt){
  int idx = blockIdx.x*256 + threadIdx.x;   // b*TT + t
  int b = idx >> 12, t = idx & (TT-1);
  #pragma unroll
  for (int j=0;j<RK;j++)
    Qt[((size_t)b*RK + j)*TT + t] = Q0[(size_t)idx*RK + j];
}

// R -> bf16 [e][f] (binary, exact)  (A-operand of gemm1m)
__global__ void k_rbf(const float4* __restrict__ R, ushort4* __restrict__ Rb){
  int i = blockIdx.x*256 + threadIdx.x;
  float4 v = R[i];
  ushort4 o; o.x=f2bf(v.x); o.y=f2bf(v.y); o.z=f2bf(v.z); o.w=f2bf(v.w);
  Rb[i] = o;
}

// R -> bf16 transposed [f][e]  (A-operand of gemm2m/ascalem)
__global__ void k_rtransb(const float* __restrict__ Rm, unsigned short* __restrict__ Rbt){
  int f = blockIdx.x, b = blockIdx.y, e = threadIdx.x;
  Rbt[((size_t)b*FF + f)*EE + e] = f2bf(Rm[((size_t)b*EE + e)*FF + f]);
}

// Omb [e][t] -> OmbT [t][e], bf16 64x64 tile transpose (one-time)
__global__ void k_omtrans(const unsigned short* __restrict__ Omb,
                          unsigned short* __restrict__ OmbT){
  __shared__ unsigned short sT[64][66];
  int b  = blockIdx.z;
  int E0 = blockIdx.y*64, T0 = blockIdx.x*64;
  int tid = threadIdx.x;
  int fi = tid >> 4;          // 0..15
  int m  = tid & 15;
  #pragma unroll
  for (int pass=0; pass<4; ++pass){
    int e = pass*16 + fi;
    ushort4 v = *(const ushort4*)(Omb + ((size_t)(b*EE + E0 + e))*TT + T0 + m*4);
    sT[e][m*4+0]=v.x; sT[e][m*4+1]=v.y; sT[e][m*4+2]=v.z; sT[e][m*4+3]=v.w;
  }
  __syncthreads();
  #pragma unroll
  for (int pass=0; pass<4; ++pass){
    int t  = pass*16 + fi;
    int e4 = m*4;
    ushort4 o;
    o.x = sT[e4+0][t]; o.y = sT[e4+1][t];
    o.z = sT[e4+2][t]; o.w = sT[e4+3][t];
    *(ushort4*)(OmbT + ((size_t)b*TT + T0 + t)*EE + E0 + e4) = o;
  }
}

// ---------------- per-iteration small kernels ----------------

__global__ void k_lhsQ(const float* __restrict__ Qt, const float* __restrict__ prm,
                       float* __restrict__ lhs, int k){
  int p = blockIdx.x, b = blockIdx.y;
  int i = 0, rem = p;
  while (rem >= i+1){ rem -= (i+1); ++i; }
  int j = rem;
  const float* qi = Qt + ((size_t)b*RK + i)*TT;
  const float* qj = Qt + ((size_t)b*RK + j)*TT;
  float a = 0.0f;
  for (int t = threadIdx.x*4; t < TT; t += 1024){
    float4 x = *(const float4*)(qi+t);
    float4 y = *(const float4*)(qj+t);
    a += x.x*y.x + x.y*y.y + x.z*y.z + x.w*y.w;
  }
  __shared__ float red[256];
  red[threadIdx.x] = a; __syncthreads();
  for (int s=128; s>0; s>>=1){
    if (threadIdx.x < s) red[threadIdx.x] += red[threadIdx.x+s];
    __syncthreads();
  }
  if (threadIdx.x==0){
    float v = red[0];
    if (i==j) v += prm[k*8+4];
    lhs[(b*RK+i)*RK + j] = v;
    lhs[(b*RK+j)*RK + i] = v;
  }
}

__global__ void k_lhsP(const float* __restrict__ P, const float* __restrict__ prm,
                       float* __restrict__ lhs, int k){
  int p = blockIdx.x, b = blockIdx.y;
  int i = 0, rem = p;
  while (rem >= i+1){ rem -= (i+1); ++i; }
  int j = rem;
  int e = threadIdx.x;
  const float* pr = P + ((size_t)b*EE + e)*RK;
  float a = pr[i]*pr[j];
  __shared__ float red[256];
  red[threadIdx.x] = a; __syncthreads();
  for (int s=128; s>0; s>>=1){
    if (threadIdx.x < s) red[threadIdx.x] += red[threadIdx.x+s];
    __syncthreads();
  }
  if (threadIdx.x==0){
    float v = red[0];
    if (i==j) v += prm[k*8+4];
    lhs[(b*RK+i)*RK + j] = v;
    lhs[(b*RK+j)*RK + i] = v;
  }
}

__global__ void k_invert(const float* __restrict__ lhs, float* __restrict__ inv){
  int b = blockIdx.x;
  __shared__ float aug[RK][2*RK];
  int tid = threadIdx.x;
  int i = tid / (2*RK), j = tid % (2*RK);
  bool act = tid < RK*2*RK;
  if (act) aug[i][j] = (j < RK) ? lhs[(b*RK+i)*RK + j] : ((j-RK)==i ? 1.0f : 0.0f);
  __syncthreads();
  for (int kk=0; kk<RK; ++kk){
    float pinv = 1.0f / aug[kk][kk];
    __syncthreads();
    if (act && i==kk) aug[i][j] *= pinv;
    __syncthreads();
    float factor = (act && i!=kk) ? aug[i][kk] : 0.0f;
    float pivrow = act ? aug[kk][j] : 0.0f;
    __syncthreads();
    if (act && i!=kk) aug[i][j] -= factor * pivrow;
    __syncthreads();
  }
  if (act && j >= RK) inv[(b*RK+i)*RK + (j-RK)] = aug[i][j];
}

__global__ void k_Pupd(const float* __restrict__ X, const float* __restrict__ Qt,
                       const float* __restrict__ inv, float* __restrict__ P){
  int e = blockIdx.x, b = blockIdx.y;
  const float* xr = X + ((size_t)b*EE + e)*TT;
  const float* qb = Qt + (size_t)b*RK*TT;
  float acc[RK];
  #pragma unroll
  for (int j=0;j<RK;j++) acc[j]=0.0f;
  for (int t = threadIdx.x*4; t < TT; t += 1024){
    float4 x = *(const float4*)(xr+t);
    #pragma unroll
    for (int j=0;j<RK;j++){
      float4 q = *(const float4*)(qb + (size_t)j*TT + t);
      acc[j] += x.x*q.x + x.y*q.y + x.z*q.z + x.w*q.w;
    }
  }
  __shared__ float partial[4][RK];
  int lane = threadIdx.x & 63, wv = threadIdx.x >> 6;
  #pragma unroll
  for (int j=0;j<RK;j++){
    float v = acc[j];
    for (int s=32;s>0;s>>=1) v += __shfl_down(v, s, 64);
    if (lane==0) partial[wv][j] = v;
  }
  __syncthreads();
  if (threadIdx.x < RK){
    int i = threadIdx.x;
    float out = 0.0f;
    #pragma unroll
    for (int j=0;j<RK;j++){
      float xq = partial[0][j]+partial[1][j]+partial[2][j]+partial[3][j];
      out += xq * inv[(b*RK+j)*RK + i];
    }
    P[((size_t)b*EE + e)*RK + i] = out;
  }
}

__global__ void k_Qupd(const float* __restrict__ X, const float* __restrict__ P,
                       const float* __restrict__ inv, float* __restrict__ Qt){
  int b = blockIdx.y;
  int t = blockIdx.x*256 + threadIdx.x;
  __shared__ float sP[EE*RK];
  __shared__ float sInv[RK*RK];
  for (int i=threadIdx.x; i<EE*RK; i+=256) sP[i] = P[(size_t)b*EE*RK + i];
  if (threadIdx.x < RK*RK) sInv[threadIdx.x] = inv[b*RK*RK + threadIdx.x];
  __syncthreads();
  float acc[RK];
  #pragma unroll
  for (int j=0;j<RK;j++) acc[j]=0.0f;
  const float* xb = X + (size_t)b*EE*TT + t;
  for (int e=0;e<EE;e++){
    float x = xb[(size_t)e*TT];
    #pragma unroll
    for (int j=0;j<RK;j++) acc[j] += x * sP[e*RK+j];
  }
  #pragma unroll
  for (int i=0;i<RK;i++){
    float q = 0.0f;
    #pragma unroll
    for (int j=0;j<RK;j++) q += acc[j]*sInv[j*RK+i];
    Qt[((size_t)b*RK + i)*TT + t] = q;
  }
}

// ---------------- A transpose: A fp32 [f][t] -> Abt bf16 [t][f] ----------------
__global__ void k_atrans(const float* __restrict__ A, unsigned short* __restrict__ Abt){
  __shared__ float sT[64][65];
  int b  = blockIdx.z;
  int F0 = blockIdx.y*64, T0 = blockIdx.x*64;
  int tid = threadIdx.x;
  int fi = tid >> 4;          // 0..15
  int m  = tid & 15;
  #pragma unroll
  for (int pass=0; pass<4; ++pass){
    int f = pass*16 + fi;
    float4 v = *(const float4*)(A + ((size_t)(b*FF + F0 + f))*TT + T0 + m*4);
    sT[f][m*4+0]=v.x; sT[f][m*4+1]=v.y; sT[f][m*4+2]=v.z; sT[f][m*4+3]=v.w;
  }
  __syncthreads();
  #pragma unroll
  for (int pass=0; pass<4; ++pass){
    int t  = pass*16 + fi;
    int f4 = m*4;
    ushort4 o;
    o.x = f2bf(sT[f4+0][t]); o.y = f2bf(sT[f4+1][t]);
    o.z = f2bf(sT[f4+2][t]); o.w = f2bf(sT[f4+3][t]);
    *(ushort4*)(Abt + ((size_t)b*TT + T0 + t)*FF + F0 + f4) = o;
  }
}

// ---------------- fused MFMA gemm1: RA = R@A, X update, residT (transposed) ----------------
// 128x128 tile, K=512 in 16 steps of 32. Epilogue writes X fp32 [e][t] and
// residT bf16 [t][e] via per-wave LDS quadrant transpose (each wave owns a
// disjoint 64x64 output quadrant -> wave-internal ordering only).
__global__ __launch_bounds__(256) void k_gemm1m(
    const unsigned short* __restrict__ Rb, const unsigned short* __restrict__ Abt,
    const float* __restrict__ Y, const unsigned short* __restrict__ Omb,
    const float* __restrict__ Qt, const float* __restrict__ P,
    const float* __restrict__ prm, float* __restrict__ X,
    unsigned short* __restrict__ residT, int k)
{
  __shared__ __align__(16) unsigned char lds[20480];
  int id = blockIdx.x;                 // 1024 blocks = b(16) x e-tile(2) x t-tile(32)
  int b  = id >> 6;
  int e0 = ((id >> 5) & 1) * 128;
  int t0 = (id & 31) * 128;
  int tid  = threadIdx.x;
  int lane = tid & 63, wid = tid >> 6;
  int lr = lane & 15, lg = lane >> 4;
  int wm = wid >> 1, wn = wid & 1;     // 2x2 waves, 64x64 out each

  f32x4 acc[4][4];
  #pragma unroll
  for (int m=0;m<4;++m)
    #pragma unroll
    for (int n=0;n<4;++n)
      #pragma unroll
      for (int i=0;i<4;++i) acc[m][n][i]=0.0f;

  if (k > 0){
    int swz  = ((lg ^ (lr & 3)) << 4);
    int aoff = (wm*64 + lr)*64 + swz;
    int boff = 8192 + (wn*64 + lr)*64 + swz;
    int c0 = tid, c1 = tid + 256;
    int r0 = c0 >> 2, s0 = c0 & 3;
    int r1 = c1 >> 2, s1 = c1 & 3;
    const unsigned short* gA0 = Rb  + ((size_t)(b*EE + e0 + r0))*FF + ((s0 ^ (r0&3))<<3);
    const unsigned short* gA1 = Rb  + ((size_t)(b*EE + e0 + r1))*FF + ((s1 ^ (r1&3))<<3);
    const unsigned short* gB0 = Abt + ((size_t)b*TT + t0 + r0)*FF   + ((s0 ^ (r0&3))<<3);
    const unsigned short* gB1 = Abt + ((size_t)b*TT + t0 + r1)*FF   + ((s1 ^ (r1&3))<<3);
    unsigned char* lA0 = lds + c0*16;
    unsigned char* lA1 = lds + c1*16;
    unsigned char* lB0 = lds + 8192 + c0*16;
    unsigned char* lB1 = lds + 8192 + c1*16;

    for (int kk=0; kk<16; ++kk){
      __syncthreads();
      int f0 = kk*32;
      gld16(gA0 + f0, lA0);
      gld16(gA1 + f0, lA1);
      gld16(gB0 + f0, lB0);
      gld16(gB1 + f0, lB1);
      asm volatile("s_waitcnt vmcnt(0)" ::: "memory");
      __syncthreads();
      bf16x8 af[4], bb[4];
      #pragma unroll
      for (int m=0;m<4;++m) af[m] = *(const bf16x8*)(lds + aoff + m*1024);
      #pragma unroll
      for (int n=0;n<4;++n) bb[n] = *(const bf16x8*)(lds + boff + n*1024);
      #pragma unroll
      for (int m=0;m<4;++m)
        #pragma unroll
        for (int n=0;n<4;++n)
          acc[m][n] = __builtin_amdgcn_mfma_f32_16x16x32_bf16(af[m], bb[n], acc[m][n], 0, 0, 0);
    }
  }

  // epilogue: wavebuf [16][68] ushort per wave at lds[wid*2176]; P/Q after.
  __syncthreads();
  unsigned short* wbuf = (unsigned short*)(lds + wid*2176);
  float* Pl = (float*)(lds + 8704);
  float* Ql = (float*)(lds + 8704 + 5120);
  for (int idx = tid; idx < 128*RK; idx += 256)
    Pl[idx] = P[((size_t)(b*EE + e0))*RK + idx];
  for (int idx = tid; idx < RK*128; idx += 256){
    int j = idx >> 7, t = idx & 127;
    Ql[idx] = Qt[((size_t)(b*RK + j))*TT + t0 + t];
  }
  __syncthreads();

  float nu = prm[k*8+2];
  #pragma unroll
  for (int n=0;n<4;++n){
    int tloc = wn*64 + n*16 + lr;
    float ql[RK];
    #pragma unroll
    for (int j=0;j<RK;++j) ql[j] = Ql[j*128 + tloc];
    asm volatile("" ::: "memory");
    #pragma unroll
    for (int m=0;m<4;++m){
      #pragma unroll
      for (int r=0;r<4;++r){
        int eloc = wm*64 + m*16 + lg*4 + r;
        float pq = 0.0f;
        #pragma unroll
        for (int j=0;j<RK;++j) pq += Pl[eloc*RK + j]*ql[j];
        float ra = acc[m][n][r];
        size_t off = ((size_t)(b*EE + e0 + eloc))*TT + t0 + tloc;
        float y = Y[off];
        float o = bf2f(Omb[off]);
        float d = y - ra, om2 = o*o;
        float x = (om2*d + nu*pq)/(om2 + nu);
        float rs = o*(y - x - ra);
        X[off] = x;
        wbuf[lr*68 + m*16 + lg*4 + r] = f2bf(rs);   // row=t within chunk, col=e within quad
      }
    }
    asm volatile("" ::: "memory");
    // wave-internal readback: 16 rows x 64 e, coalesced 128B row chunks
    #pragma unroll
    for (int j2=0;j2<4;++j2){
      int row = j2*4 + lg;
      int c4  = lr*4;
      ushort4 vv = *(const ushort4*)(wbuf + row*68 + c4);
      *(ushort4*)(residT + ((size_t)b*TT + t0 + wn*64 + n*16 + row)*EE + e0 + wm*64 + c4) = vv;
    }
    asm volatile("" ::: "memory");
  }
}

__device__ __forceinline__ float aupd(float a, float g, unsigned short asu,
                                      float mu, float gamma){
  float as = bf2f(asu);
  bool no = (as == 0.0f);
  float rs = 1.0f / (no ? 1.0f : as);
  float ba = a + g*rs;
  float ad = copysignf(fmaxf(fabsf(ba) - mu*rs, 0.0f), ba);
  if (no) ad = 0.0f;
  return a + gamma*(ad - a);
}

// ---------------- MFMA gemm2: G = Rt@resid (via residT), fused A update ----------------
// 128x128 output tile (f x t), K=E=256 in 8 steps of 32.
__global__ __launch_bounds__(256) void k_gemm2m(
    const unsigned short* __restrict__ Rbt, const unsigned short* __restrict__ residT,
    const unsigned short* __restrict__ As, const float* __restrict__ prm,
    float* __restrict__ A, int k)
{
  __shared__ __align__(16) unsigned char lds[16384];
  int id = blockIdx.x;                 // 2048 = b(16) x f-tile(4) x t-tile(32)
  int b  = id >> 7;
  int f0 = ((id >> 5) & 3) * 128;
  int t0 = (id & 31) * 128;
  int tid  = threadIdx.x;
  int lane = tid & 63, wid = tid >> 6;
  int lr = lane & 15, lg = lane >> 4;
  int wm = wid >> 1, wn = wid & 1;

  f32x4 acc[4][4];
  #pragma unroll
  for (int m=0;m<4;++m)
    #pragma unroll
    for (int n=0;n<4;++n)
      #pragma unroll
      for (int i=0;i<4;++i) acc[m][n][i]=0.0f;

  int swz  = ((lg ^ (lr & 3)) << 4);
  int aoff = (wm*64 + lr)*64 + swz;
  int boff = 8192 + (wn*64 + lr)*64 + swz;
  int c0 = tid, c1 = tid + 256;
  int r0 = c0 >> 2, s0 = c0 & 3;
  int r1 = c1 >> 2, s1 = c1 & 3;
  const unsigned short* gA0 = Rbt    + ((size_t)(b*FF + f0 + r0))*EE + ((s0 ^ (r0&3))<<3);
  const unsigned short* gA1 = Rbt    + ((size_t)(b*FF + f0 + r1))*EE + ((s1 ^ (r1&3))<<3);
  const unsigned short* gB0 = residT + ((size_t)b*TT + t0 + r0)*EE   + ((s0 ^ (r0&3))<<3);
  const unsigned short* gB1 = residT + ((size_t)b*TT + t0 + r1)*EE   + ((s1 ^ (r1&3))<<3);
  unsigned char* lA0 = lds + c0*16;
  unsigned char* lA1 = lds + c1*16;
  unsigned char* lB0 = lds + 8192 + c0*16;
  unsigned char* lB1 = lds + 8192 + c1*16;

  for (int kk=0; kk<8; ++kk){
    __syncthreads();
    int eoff = kk*32;
    gld16(gA0 + eoff, lA0);
    gld16(gA1 + eoff, lA1);
    gld16(gB0 + eoff, lB0);
    gld16(gB1 + eoff, lB1);
    asm volatile("s_waitcnt vmcnt(0)" ::: "memory");
    __syncthreads();
    bf16x8 af[4], bb[4];
    #pragma unroll
    for (int m=0;m<4;++m) af[m] = *(const bf16x8*)(lds + aoff + m*1024);
    #pragma unroll
    for (int n=0;n<4;++n) bb[n] = *(const bf16x8*)(lds + boff + n*1024);
    #pragma unroll
    for (int m=0;m<4;++m)
      #pragma unroll
      for (int n=0;n<4;++n)
        acc[m][n] = __builtin_amdgcn_mfma_f32_16x16x32_bf16(af[m], bb[n], acc[m][n], 0, 0, 0);
  }

  float mu = prm[k*8+1], gamma = prm[k*8+3];
  #pragma unroll
  for (int m=0;m<4;++m){
    #pragma unroll
    for (int r=0;r<4;++r){
      int floc = wm*64 + m*16 + lg*4 + r;
      size_t rowoff = ((size_t)(b*FF + f0 + floc))*TT + t0;
      #pragma unroll
      for (int n=0;n<4;++n){
        int tloc = wn*64 + n*16 + lr;
        size_t off = rowoff + tloc;
        float a = A[off];
        A[off] = aupd(a, acc[m][n][r], As[off], mu, gamma);
      }
    }
  }
}

// ---------------- MFMA A-scale (one-time): As = R^T @ Om (binary inputs) ----------------
__global__ __launch_bounds__(256) void k_ascalem(
    const unsigned short* __restrict__ Rbt, const unsigned short* __restrict__ OmbT,
    unsigned short* __restrict__ As)
{
  __shared__ __align__(16) unsigned char lds[16384];
  int id = blockIdx.x;                 // 2048 = b(16) x f-tile(4) x t-tile(32)
  int b  = id >> 7;
  int f0 = ((id >> 5) & 3) * 128;
  int t0 = (id & 31) * 128;
  int tid  = threadIdx.x;
  int lane = tid & 63, wid = tid >> 6;
  int lr = lane & 15, lg = lane >> 4;
  int wm = wid >> 1, wn = wid & 1;

  f32x4 acc[4][4];
  #pragma unroll
  for (int m=0;m<4;++m)
    #pragma unroll
    for (int n=0;n<4;++n)
      #pragma unroll
      for (int i=0;i<4;++i) acc[m][n][i]=0.0f;

  int swz  = ((lg ^ (lr & 3)) << 4);
  int aoff = (wm*64 + lr)*64 + swz;
  int boff = 8192 + (wn*64 + lr)*64 + swz;
  int c0 = tid, c1 = tid + 256;
  int r0 = c0 >> 2, s0 = c0 & 3;
  int r1 = c1 >> 2, s1 = c1 & 3;
  const unsigned short* gA0 = Rbt  + ((size_t)(b*FF + f0 + r0))*EE + ((s0 ^ (r0&3))<<3);
  const unsigned short* gA1 = Rbt  + ((size_t)(b*FF + f0 + r1))*EE + ((s1 ^ (r1&3))<<3);
  const unsigned short* gB0 = OmbT + ((size_t)b*TT + t0 + r0)*EE   + ((s0 ^ (r0&3))<<3);
  const unsigned short* gB1 = OmbT + ((size_t)b*TT + t0 + r1)*EE   + ((s1 ^ (r1&3))<<3);
  unsigned char* lA0 = lds + c0*16;
  unsigned char* lA1 = lds + c1*16;
  unsigned char* lB0 = lds + 8192 + c0*16;
  unsigned char* lB1 = lds + 8192 + c1*16;

  for (int kk=0; kk<8; ++kk){
    __syncthreads();
    int eoff = kk*32;
    gld16(gA0 + eoff, lA0);
    gld16(gA1 + eoff, lA1);
    gld16(gB0 + eoff, lB0);
    gld16(gB1 + eoff, lB1);
    asm volatile("s_waitcnt vmcnt(0)" ::: "memory");
    __syncthreads();
    bf16x8 af[4], bb[4];
    #pragma unroll
    for (int m=0;m<4;++m) af[m] = *(const bf16x8*)(lds + aoff + m*1024);
    #pragma unroll
    for (int n=0;n<4;++n) bb[n] = *(const bf16x8*)(lds + boff + n*1024);
    #pragma unroll
    for (int m=0;m<4;++m)
      #pragma unroll
      for (int n=0;n<4;++n)
        acc[m][n] = __builtin_amdgcn_mfma_f32_16x16x32_bf16(af[m], bb[n], acc[m][n], 0, 0, 0);
  }

  #pragma unroll
  for (int m=0;m<4;++m){
    #pragma unroll
    for (int r=0;r<4;++r){
      int floc = wm*64 + m*16 + lg*4 + r;
      size_t rowoff = ((size_t)(b*FF + f0 + floc))*TT + t0;
      #pragma unroll
      for (int n=0;n<4;++n){
        int tloc = wn*64 + n*16 + lr;
        As[rowoff + tloc] = f2bf(acc[m][n][r]);   // integer counts <=256, exact
      }
    }
  }
}

// ---------------- launch ----------------

extern "C" void kernel_launch(void* const* d_in, const int* in_sizes, int n_in,
                              void* d_out, int out_size, void* d_ws, size_t ws_size,
                              hipStream_t stream){
  const float* Y   = (const float*)d_in[0];
  const float* Rm  = (const float*)d_in[1];
  const float* Om  = (const float*)d_in[2];
  const float* P0  = (const float*)d_in[3];
  const float* Q0  = (const float*)d_in[4];
  const float* lam = (const float*)d_in[5];
  const float* mu  = (const float*)d_in[6];
  const float* nu  = (const float*)d_in[7];
  const float* gl  = (const float*)d_in[8];
  float* A = (float*)d_out;

  char* ws = (char*)d_ws;
  const size_t X_OFF    = 0;
  const size_t REST_OFF = X_OFF    + (size_t)BB*EE*TT*4;   // X: 64 MiB
  const size_t OMB_OFF  = REST_OFF + (size_t)BB*TT*EE*2;   // residT bf16 [t][e]: 32 MiB
  const size_t AS_OFF   = OMB_OFF  + (size_t)BB*EE*TT*2;   // Omb bf16: 32 MiB
  const size_t QT_OFF   = AS_OFF   + (size_t)BB*FF*TT*2;   // As bf16: 64 MiB
  const size_t P_OFF    = QT_OFF   + (size_t)BB*RK*TT*4;
  const size_t LHS_OFF  = P_OFF    + (size_t)BB*EE*RK*4;
  const size_t INV_OFF  = LHS_OFF  + (size_t)BB*RK*RK*4;
  const size_t PRM_OFF  = INV_OFF  + (size_t)BB*RK*RK*4;
  const size_t RB_OFF   = PRM_OFF  + 4096;                 // Rb bf16 [e][f]: 4 MiB
  const size_t RBT_OFF  = RB_OFF   + (size_t)BB*EE*FF*2;   // Rbt bf16 [f][e]: 4 MiB
  const size_t OMBT_OFF = RBT_OFF  + (size_t)BB*FF*EE*2;   // OmbT bf16 [t][e]: 32 MiB
  const size_t ABT_OFF  = OMBT_OFF + (size_t)BB*TT*EE*2;   // Abt bf16 [t][f]: 64 MiB

  float* X    = (float*)(ws + X_OFF);
  unsigned short* residT = (unsigned short*)(ws + REST_OFF);
  unsigned short* Omb    = (unsigned short*)(ws + OMB_OFF);
  unsigned short* As     = (unsigned short*)(ws + AS_OFF);
  float* Qt   = (float*)(ws + QT_OFF);
  float* P    = (float*)(ws + P_OFF);
  float* lhs  = (float*)(ws + LHS_OFF);
  float* inv  = (float*)(ws + INV_OFF);
  float* prm  = (float*)(ws + PRM_OFF);
  unsigned short* Rb   = (unsigned short*)(ws + RB_OFF);
  unsigned short* Rbt  = (unsigned short*)(ws + RBT_OFF);
  unsigned short* OmbT = (unsigned short*)(ws + OMBT_OFF);
  unsigned short* Abt  = (unsigned short*)(ws + ABT_OFF);

  (void)P0; (void)Om; (void)in_sizes; (void)n_in; (void)ws_size;

  hipMemsetAsync(d_out, 0, (size_t)out_size*sizeof(float), stream);
  k_params<<<1, 64, 0, stream>>>(lam, mu, nu, gl, prm);
  k_initX<<<BB*EE*TT/4/256, 256, 0, stream>>>((const float4*)Y, (const float4*)Om,
                                              (float4*)X, (ushort4*)Omb);
  k_qtrans<<<BB*TT/256, 256, 0, stream>>>(Q0, Qt);
  k_rbf<<<BB*EE*FF/4/256, 256, 0, stream>>>((const float4*)Rm, (ushort4*)Rb);
  k_rtransb<<<dim3(FF, BB), 256, 0, stream>>>(Rm, Rbt);
  k_omtrans<<<dim3(TT/64, EE/64, BB), 256, 0, stream>>>(Omb, OmbT);
  k_ascalem<<<2048, 256, 0, stream>>>(Rbt, OmbT, As);

  for (int k=0; k<NIT; ++k){
    k_lhsQ  <<<dim3(55, BB), 256, 0, stream>>>(Qt, prm, lhs, k);
    k_invert<<<BB, 256, 0, stream>>>(lhs, inv);
    k_Pupd  <<<dim3(EE, BB), 256, 0, stream>>>(X, Qt, inv, P);
    k_lhsP  <<<dim3(55, BB), 256, 0, stream>>>(P, prm, lhs, k);
    k_invert<<<BB, 256, 0, stream>>>(lhs, inv);
    k_Qupd  <<<dim3(TT/256, BB), 256, 0, stream>>>(X, P, inv, Qt);
    if (k > 0)
      k_atrans<<<dim3(TT/64, FF/64, BB), 256, 0, stream>>>(A, Abt);
    k_gemm1m<<<BB*2*32, 256, 0, stream>>>(Rb, Abt, Y, Omb, Qt, P, prm, X, residT, k);
    k_gemm2m<<<2048, 256, 0, stream>>>(Rbt, residT, As, prm, A, k);
  }
}

// Round 3
// 1796.878 us; speedup vs baseline: 1.3703x; 1.1094x over previous
//
#include <hip/hip_runtime.h>
#include <stdint.h>

#define BB 16
#define EE 256
#define TT 4096
#define FF 512
#define RK 10
#define NIT 5

typedef short bf16x8 __attribute__((ext_vector_type(8)));
typedef float f32x4  __attribute__((ext_vector_type(4)));

__device__ __forceinline__ unsigned short f2bf(float x){
  unsigned int u = __float_as_uint(x);
  unsigned int r = (u + 0x7FFFu + ((u >> 16) & 1u)) >> 16;
  return (unsigned short)r;
}
__device__ __forceinline__ float bf2f(unsigned short s){
  return __uint_as_float(((unsigned int)s) << 16);
}

// async global->LDS, 16B per lane; LDS dest linear in lane order.
__device__ __forceinline__ void gld16(const void* g, void* l){
  __builtin_amdgcn_global_load_lds((const __attribute__((address_space(1))) unsigned int*)g,
                                   (__attribute__((address_space(3))) unsigned int*)l,
                                   16, 0, 0);
}

// slot swizzle (involution): source slot for (row r, phys slot s), ushort units <<3
__device__ __forceinline__ int ssw(int r, int s){
  return ((s ^ (r & 3) ^ ((r >> 2) & 3)) << 3);
}

// ---------------- setup kernels ----------------

__global__ void k_params(const float* lam_log, const float* mu_log,
                         const float* nu_log, const float* gl, float* prm){
  int k = threadIdx.x;
  if (k < NIT){
    float lam = expf(lam_log[k]);
    float mu  = expf(mu_log[k]);
    float nu  = expf(nu_log[k]);
    float gam = 1.0f/(1.0f+expf(-gl[k]));
    prm[k*8+0]=lam; prm[k*8+1]=mu; prm[k*8+2]=nu; prm[k*8+3]=gam; prm[k*8+4]=lam/nu;
  }
}

// X = Om*Y ; also emit Omega as bf16 (binary -> exact)
__global__ void k_initX(const float4* __restrict__ Y, const float4* __restrict__ Om,
                        float4* __restrict__ X, ushort4* __restrict__ Omb){
  int i = blockIdx.x*256 + threadIdx.x;
  float4 y = Y[i], o = Om[i];
  X[i] = make_float4(y.x*o.x, y.y*o.y, y.z*o.z, y.w*o.w);
  ushort4 ob; ob.x=f2bf(o.x); ob.y=f2bf(o.y); ob.z=f2bf(o.z); ob.w=f2bf(o.w);
  Omb[i] = ob;
}

__global__ void k_qtrans(const float* __restrict__ Q0, float* __restrict__ Qt){
  int idx = blockIdx.x*256 + threadIdx.x;   // b*TT + t
  int b = idx >> 12, t = idx & (TT-1);
  #pragma unroll
  for (int j=0;j<RK;j++)
    Qt[((size_t)b*RK + j)*TT + t] = Q0[(size_t)idx*RK + j];
}

// R -> bf16 [e][f] (binary, exact)  (B-operand of gemm1m)
__global__ void k_rbf(const float4* __restrict__ R, ushort4* __restrict__ Rb){
  int i = blockIdx.x*256 + threadIdx.x;
  float4 v = R[i];
  ushort4 o; o.x=f2bf(v.x); o.y=f2bf(v.y); o.z=f2bf(v.z); o.w=f2bf(v.w);
  Rb[i] = o;
}

// R -> bf16 transposed [f][e]  (B-operand of gemm2m/ascalem)
__global__ void k_rtransb(const float* __restrict__ Rm, unsigned short* __restrict__ Rbt){
  int f = blockIdx.x, b = blockIdx.y, e = threadIdx.x;
  Rbt[((size_t)b*FF + f)*EE + e] = f2bf(Rm[((size_t)b*EE + e)*FF + f]);
}

// Omb [e][t] -> OmbT [t][e], bf16 64x64 tile transpose (one-time)
__global__ void k_omtrans(const unsigned short* __restrict__ Omb,
                          unsigned short* __restrict__ OmbT){
  __shared__ unsigned short sT[64][66];
  int b  = blockIdx.z;
  int E0 = blockIdx.y*64, T0 = blockIdx.x*64;
  int tid = threadIdx.x;
  int fi = tid >> 4;          // 0..15
  int m  = tid & 15;
  #pragma unroll
  for (int pass=0; pass<4; ++pass){
    int e = pass*16 + fi;
    ushort4 v = *(const ushort4*)(Omb + ((size_t)(b*EE + E0 + e))*TT + T0 + m*4);
    sT[e][m*4+0]=v.x; sT[e][m*4+1]=v.y; sT[e][m*4+2]=v.z; sT[e][m*4+3]=v.w;
  }
  __syncthreads();
  #pragma unroll
  for (int pass=0; pass<4; ++pass){
    int t  = pass*16 + fi;
    int e4 = m*4;
    ushort4 o;
    o.x = sT[e4+0][t]; o.y = sT[e4+1][t];
    o.z = sT[e4+2][t]; o.w = sT[e4+3][t];
    *(ushort4*)(OmbT + ((size_t)b*TT + T0 + t)*EE + E0 + e4) = o;
  }
}

// ---------------- per-iteration small kernels ----------------

__global__ void k_lhsQ(const float* __restrict__ Qt, const float* __restrict__ prm,
                       float* __restrict__ lhs, int k){
  int p = blockIdx.x, b = blockIdx.y;
  int i = 0, rem = p;
  while (rem >= i+1){ rem -= (i+1); ++i; }
  int j = rem;
  const float* qi = Qt + ((size_t)b*RK + i)*TT;
  const float* qj = Qt + ((size_t)b*RK + j)*TT;
  float a = 0.0f;
  for (int t = threadIdx.x*4; t < TT; t += 1024){
    float4 x = *(const float4*)(qi+t);
    float4 y = *(const float4*)(qj+t);
    a += x.x*y.x + x.y*y.y + x.z*y.z + x.w*y.w;
  }
  __shared__ float red[256];
  red[threadIdx.x] = a; __syncthreads();
  for (int s=128; s>0; s>>=1){
    if (threadIdx.x < s) red[threadIdx.x] += red[threadIdx.x+s];
    __syncthreads();
  }
  if (threadIdx.x==0){
    float v = red[0];
    if (i==j) v += prm[k*8+4];
    lhs[(b*RK+i)*RK + j] = v;
    lhs[(b*RK+j)*RK + i] = v;
  }
}

__global__ void k_lhsP(const float* __restrict__ P, const float* __restrict__ prm,
                       float* __restrict__ lhs, int k){
  int p = blockIdx.x, b = blockIdx.y;
  int i = 0, rem = p;
  while (rem >= i+1){ rem -= (i+1); ++i; }
  int j = rem;
  int e = threadIdx.x;
  const float* pr = P + ((size_t)b*EE + e)*RK;
  float a = pr[i]*pr[j];
  __shared__ float red[256];
  red[threadIdx.x] = a; __syncthreads();
  for (int s=128; s>0; s>>=1){
    if (threadIdx.x < s) red[threadIdx.x] += red[threadIdx.x+s];
    __syncthreads();
  }
  if (threadIdx.x==0){
    float v = red[0];
    if (i==j) v += prm[k*8+4];
    lhs[(b*RK+i)*RK + j] = v;
    lhs[(b*RK+j)*RK + i] = v;
  }
}

__global__ void k_invert(const float* __restrict__ lhs, float* __restrict__ inv){
  int b = blockIdx.x;
  __shared__ float aug[RK][2*RK];
  int tid = threadIdx.x;
  int i = tid / (2*RK), j = tid % (2*RK);
  bool act = tid < RK*2*RK;
  if (act) aug[i][j] = (j < RK) ? lhs[(b*RK+i)*RK + j] : ((j-RK)==i ? 1.0f : 0.0f);
  __syncthreads();
  for (int kk=0; kk<RK; ++kk){
    float pinv = 1.0f / aug[kk][kk];
    __syncthreads();
    if (act && i==kk) aug[i][j] *= pinv;
    __syncthreads();
    float factor = (act && i!=kk) ? aug[i][kk] : 0.0f;
    float pivrow = act ? aug[kk][j] : 0.0f;
    __syncthreads();
    if (act && i!=kk) aug[i][j] -= factor * pivrow;
    __syncthreads();
  }
  if (act && j >= RK) inv[(b*RK+i)*RK + (j-RK)] = aug[i][j];
}

__global__ void k_Pupd(const float* __restrict__ X, const float* __restrict__ Qt,
                       const float* __restrict__ inv, float* __restrict__ P){
  int e = blockIdx.x, b = blockIdx.y;
  const float* xr = X + ((size_t)b*EE + e)*TT;
  const float* qb = Qt + (size_t)b*RK*TT;
  float acc[RK];
  #pragma unroll
  for (int j=0;j<RK;j++) acc[j]=0.0f;
  for (int t = threadIdx.x*4; t < TT; t += 1024){
    float4 x = *(const float4*)(xr+t);
    #pragma unroll
    for (int j=0;j<RK;j++){
      float4 q = *(const float4*)(qb + (size_t)j*TT + t);
      acc[j] += x.x*q.x + x.y*q.y + x.z*q.z + x.w*q.w;
    }
  }
  __shared__ float partial[4][RK];
  int lane = threadIdx.x & 63, wv = threadIdx.x >> 6;
  #pragma unroll
  for (int j=0;j<RK;j++){
    float v = acc[j];
    for (int s=32;s>0;s>>=1) v += __shfl_down(v, s, 64);
    if (lane==0) partial[wv][j] = v;
  }
  __syncthreads();
  if (threadIdx.x < RK){
    int i = threadIdx.x;
    float out = 0.0f;
    #pragma unroll
    for (int j=0;j<RK;j++){
      float xq = partial[0][j]+partial[1][j]+partial[2][j]+partial[3][j];
      out += xq * inv[(b*RK+j)*RK + i];
    }
    P[((size_t)b*EE + e)*RK + i] = out;
  }
}

__global__ void k_Qupd(const float* __restrict__ X, const float* __restrict__ P,
                       const float* __restrict__ inv, float* __restrict__ Qt){
  int b = blockIdx.y;
  int t = blockIdx.x*256 + threadIdx.x;
  __shared__ float sP[EE*RK];
  __shared__ float sInv[RK*RK];
  for (int i=threadIdx.x; i<EE*RK; i+=256) sP[i] = P[(size_t)b*EE*RK + i];
  if (threadIdx.x < RK*RK) sInv[threadIdx.x] = inv[b*RK*RK + threadIdx.x];
  __syncthreads();
  float acc[RK];
  #pragma unroll
  for (int j=0;j<RK;j++) acc[j]=0.0f;
  const float* xb = X + (size_t)b*EE*TT + t;
  for (int e=0;e<EE;e++){
    float x = xb[(size_t)e*TT];
    #pragma unroll
    for (int j=0;j<RK;j++) acc[j] += x * sP[e*RK+j];
  }
  #pragma unroll
  for (int i=0;i<RK;i++){
    float q = 0.0f;
    #pragma unroll
    for (int j=0;j<RK;j++) q += acc[j]*sInv[j*RK+i];
    Qt[((size_t)b*RK + i)*TT + t] = q;
  }
}

// ---------------- fused MFMA gemm1 (swapped orientation: M=t, N=e) ----------------
// A-operand = Abt [t][f], B-operand = Rb [e][f]; D[t][e] = RA[e][t].
// Per-thread fragment: 4 consecutive t (reg idx) at fixed e -> float4 epilogue.
// Writes X fp32 [e][t] (float4) and residT bf16 [t][e] (per-wave LDS transpose).
__global__ __launch_bounds__(256) void k_gemm1m(
    const unsigned short* __restrict__ Abt, const unsigned short* __restrict__ Rb,
    const float* __restrict__ Y, const unsigned short* __restrict__ Omb,
    const float* __restrict__ Qt, const float* __restrict__ P,
    const float* __restrict__ prm, float* __restrict__ X,
    unsigned short* __restrict__ residT, int k)
{
  __shared__ __align__(16) unsigned char lds[20480];
  int id = blockIdx.x;                 // 1024 blocks = b(16) x e-tile(2) x t-tile(32)
  int b  = id >> 6;
  int e0 = ((id >> 5) & 1) * 128;
  int t0 = (id & 31) * 128;
  int tid  = threadIdx.x;
  int lane = tid & 63, wid = tid >> 6;
  int lr = lane & 15, lg = lane >> 4;
  int wm = wid >> 1, wn = wid & 1;     // wm: t-quad, wn: e-quad (64x64 each)

  f32x4 acc[4][4];
  #pragma unroll
  for (int m=0;m<4;++m)
    #pragma unroll
    for (int n=0;n<4;++n)
      #pragma unroll
      for (int i=0;i<4;++i) acc[m][n][i]=0.0f;

  if (k > 0){
    int swz  = ((lg ^ (lr & 3) ^ ((lr >> 2) & 3)) << 4);
    int aoff = (wm*64 + lr)*64 + swz;            // A region: rows t
    int boff = 8192 + (wn*64 + lr)*64 + swz;     // B region: rows e
    int c0 = tid, c1 = tid + 256;
    int r0 = c0 >> 2, s0 = c0 & 3;
    int r1 = c1 >> 2, s1 = c1 & 3;
    const unsigned short* gA0 = Abt + ((size_t)b*TT + t0 + r0)*FF + ssw(r0,s0);
    const unsigned short* gA1 = Abt + ((size_t)b*TT + t0 + r1)*FF + ssw(r1,s1);
    const unsigned short* gB0 = Rb  + ((size_t)(b*EE + e0 + r0))*FF + ssw(r0,s0);
    const unsigned short* gB1 = Rb  + ((size_t)(b*EE + e0 + r1))*FF + ssw(r1,s1);
    unsigned char* lA0 = lds + c0*16;
    unsigned char* lA1 = lds + c1*16;
    unsigned char* lB0 = lds + 8192 + c0*16;
    unsigned char* lB1 = lds + 8192 + c1*16;

    for (int kk=0; kk<16; ++kk){
      __syncthreads();
      int f0k = kk*32;
      gld16(gA0 + f0k, lA0);
      gld16(gA1 + f0k, lA1);
      gld16(gB0 + f0k, lB0);
      gld16(gB1 + f0k, lB1);
      asm volatile("s_waitcnt vmcnt(0)" ::: "memory");
      __syncthreads();
      bf16x8 af[4], bb[4];
      #pragma unroll
      for (int m=0;m<4;++m) af[m] = *(const bf16x8*)(lds + aoff + m*1024);
      #pragma unroll
      for (int n=0;n<4;++n) bb[n] = *(const bf16x8*)(lds + boff + n*1024);
      #pragma unroll
      for (int m=0;m<4;++m)
        #pragma unroll
        for (int n=0;n<4;++n)
          acc[m][n] = __builtin_amdgcn_mfma_f32_16x16x32_bf16(af[m], bb[n], acc[m][n], 0, 0, 0);
    }
  }

  // epilogue: wbuf [16][68] ushort per wave; P/Q fp32 blocks after.
  __syncthreads();
  unsigned short* wbuf = (unsigned short*)(lds + wid*2176);
  float* Pl = (float*)(lds + 8704);
  float* Ql = (float*)(lds + 8704 + 5120);
  for (int idx = tid; idx < 128*RK; idx += 256)
    Pl[idx] = P[((size_t)(b*EE + e0))*RK + idx];
  for (int idx = tid; idx < RK*128; idx += 256){
    int j = idx >> 7, t = idx & 127;
    Ql[idx] = Qt[((size_t)(b*RK + j))*TT + t0 + t];
  }
  __syncthreads();

  float nu = prm[k*8+2];
  #pragma unroll
  for (int m=0;m<4;++m){
    int tq = wm*64 + m*16 + lg*4;                // t offset within block
    float4 ql4[RK];
    #pragma unroll
    for (int j=0;j<RK;++j) ql4[j] = *(const float4*)(Ql + j*128 + tq);
    asm volatile("" ::: "memory");
    #pragma unroll
    for (int n=0;n<4;++n){
      int eloc = wn*64 + n*16 + lr;
      const float* pr = Pl + eloc*RK;
      float4 pq = {0,0,0,0};
      #pragma unroll
      for (int j=0;j<RK;++j){
        float pj = pr[j];
        pq.x += pj*ql4[j].x; pq.y += pj*ql4[j].y;
        pq.z += pj*ql4[j].z; pq.w += pj*ql4[j].w;
      }
      f32x4 ra = acc[m][n];
      size_t off = ((size_t)(b*EE + e0 + eloc))*TT + t0 + tq;
      float4 y = *(const float4*)(Y + off);
      ushort4 ou = *(const ushort4*)(Omb + off);
      float4 xo; float rs0, rs1, rs2, rs3;
      {
        float o = bf2f(ou.x), om2 = o*o, d = y.x - ra[0];
        xo.x = (om2*d + nu*pq.x)/(om2 + nu); rs0 = o*(y.x - xo.x - ra[0]);
      }{
        float o = bf2f(ou.y), om2 = o*o, d = y.y - ra[1];
        xo.y = (om2*d + nu*pq.y)/(om2 + nu); rs1 = o*(y.y - xo.y - ra[1]);
      }{
        float o = bf2f(ou.z), om2 = o*o, d = y.z - ra[2];
        xo.z = (om2*d + nu*pq.z)/(om2 + nu); rs2 = o*(y.z - xo.z - ra[2]);
      }{
        float o = bf2f(ou.w), om2 = o*o, d = y.w - ra[3];
        xo.w = (om2*d + nu*pq.w)/(om2 + nu); rs3 = o*(y.w - xo.w - ra[3]);
      }
      *(float4*)(X + off) = xo;
      int wc = n*16 + lr;
      wbuf[(lg*4+0)*68 + wc] = f2bf(rs0);
      wbuf[(lg*4+1)*68 + wc] = f2bf(rs1);
      wbuf[(lg*4+2)*68 + wc] = f2bf(rs2);
      wbuf[(lg*4+3)*68 + wc] = f2bf(rs3);
    }
    asm volatile("" ::: "memory");
    // readback: 16 t-rows x 64 e, coalesced 128B rows
    #pragma unroll
    for (int j2=0;j2<4;++j2){
      int row = j2*4 + lg;
      int c4  = lr*4;
      ushort4 vv = *(const ushort4*)(wbuf + row*68 + c4);
      *(ushort4*)(residT + ((size_t)b*TT + t0 + wm*64 + m*16 + row)*EE + e0 + wn*64 + c4) = vv;
    }
    asm volatile("" ::: "memory");
  }
}

__device__ __forceinline__ float aupd(float a, float g, unsigned short asu,
                                      float mu, float gamma){
  float as = bf2f(asu);
  bool no = (as == 0.0f);
  float rs = 1.0f / (no ? 1.0f : as);
  float ba = a + g*rs;
  float ad = copysignf(fmaxf(fabsf(ba) - mu*rs, 0.0f), ba);
  if (no) ad = 0.0f;
  return a + gamma*(ad - a);
}

// ---------------- MFMA gemm2 (swapped: M=t, N=f): G = R^T@resid, A update, Abt emit ----
// A-operand = residT [t][e], B-operand = Rbt [f][e]; D[t][f] = G[f][t].
// Per-thread: 4 consecutive t at fixed f -> float4 A RMW, ushort4 As.
// Emits Abt bf16 [t][f] for next iteration's gemm1m (skipped at final iter).
__global__ __launch_bounds__(256) void k_gemm2m(
    const unsigned short* __restrict__ residT, const unsigned short* __restrict__ Rbt,
    const unsigned short* __restrict__ As, const float* __restrict__ prm,
    float* __restrict__ A, unsigned short* __restrict__ Abt, int k)
{
  __shared__ __align__(16) unsigned char lds[16384];
  int id = blockIdx.x;                 // 2048 = b(16) x f-tile(4) x t-tile(32)
  int b  = id >> 7;
  int f0 = ((id >> 5) & 3) * 128;
  int t0 = (id & 31) * 128;
  int tid  = threadIdx.x;
  int lane = tid & 63, wid = tid >> 6;
  int lr = lane & 15, lg = lane >> 4;
  int wm = wid >> 1, wn = wid & 1;     // wm: t-quad, wn: f-quad

  f32x4 acc[4][4];
  #pragma unroll
  for (int m=0;m<4;++m)
    #pragma unroll
    for (int n=0;n<4;++n)
      #pragma unroll
      for (int i=0;i<4;++i) acc[m][n][i]=0.0f;

  int swz  = ((lg ^ (lr & 3) ^ ((lr >> 2) & 3)) << 4);
  int aoff = (wm*64 + lr)*64 + swz;
  int boff = 8192 + (wn*64 + lr)*64 + swz;
  int c0 = tid, c1 = tid + 256;
  int r0 = c0 >> 2, s0 = c0 & 3;
  int r1 = c1 >> 2, s1 = c1 & 3;
  const unsigned short* gA0 = residT + ((size_t)b*TT + t0 + r0)*EE + ssw(r0,s0);
  const unsigned short* gA1 = residT + ((size_t)b*TT + t0 + r1)*EE + ssw(r1,s1);
  const unsigned short* gB0 = Rbt    + ((size_t)(b*FF + f0 + r0))*EE + ssw(r0,s0);
  const unsigned short* gB1 = Rbt    + ((size_t)(b*FF + f0 + r1))*EE + ssw(r1,s1);
  unsigned char* lA0 = lds + c0*16;
  unsigned char* lA1 = lds + c1*16;
  unsigned char* lB0 = lds + 8192 + c0*16;
  unsigned char* lB1 = lds + 8192 + c1*16;

  for (int kk=0; kk<8; ++kk){
    __syncthreads();
    int eoff = kk*32;
    gld16(gA0 + eoff, lA0);
    gld16(gA1 + eoff, lA1);
    gld16(gB0 + eoff, lB0);
    gld16(gB1 + eoff, lB1);
    asm volatile("s_waitcnt vmcnt(0)" ::: "memory");
    __syncthreads();
    bf16x8 af[4], bb[4];
    #pragma unroll
    for (int m=0;m<4;++m) af[m] = *(const bf16x8*)(lds + aoff + m*1024);
    #pragma unroll
    for (int n=0;n<4;++n) bb[n] = *(const bf16x8*)(lds + boff + n*1024);
    #pragma unroll
    for (int m=0;m<4;++m)
      #pragma unroll
      for (int n=0;n<4;++n)
        acc[m][n] = __builtin_amdgcn_mfma_f32_16x16x32_bf16(af[m], bb[n], acc[m][n], 0, 0, 0);
  }

  __syncthreads();                      // staging LDS reused as wbuf below
  unsigned short* wbuf = (unsigned short*)(lds + wid*2176);
  float mu = prm[k*8+1], gamma = prm[k*8+3];
  bool emit = (k < NIT-1);
  #pragma unroll
  for (int m=0;m<4;++m){
    int tq = wm*64 + m*16 + lg*4;
    #pragma unroll
    for (int n=0;n<4;++n){
      int floc = wn*64 + n*16 + lr;
      size_t off = ((size_t)(b*FF + f0 + floc))*TT + t0 + tq;
      float4 a = *(const float4*)(A + off);
      ushort4 as4 = *(const ushort4*)(As + off);
      f32x4 g = acc[m][n];
      float4 an;
      an.x = aupd(a.x, g[0], as4.x, mu, gamma);
      an.y = aupd(a.y, g[1], as4.y, mu, gamma);
      an.z = aupd(a.z, g[2], as4.z, mu, gamma);
      an.w = aupd(a.w, g[3], as4.w, mu, gamma);
      *(float4*)(A + off) = an;
      if (emit){
        int wc = n*16 + lr;
        wbuf[(lg*4+0)*68 + wc] = f2bf(an.x);
        wbuf[(lg*4+1)*68 + wc] = f2bf(an.y);
        wbuf[(lg*4+2)*68 + wc] = f2bf(an.z);
        wbuf[(lg*4+3)*68 + wc] = f2bf(an.w);
      }
    }
    asm volatile("" ::: "memory");
    if (emit){
      #pragma unroll
      for (int j2=0;j2<4;++j2){
        int row = j2*4 + lg;
        int c4  = lr*4;
        ushort4 vv = *(const ushort4*)(wbuf + row*68 + c4);
        *(ushort4*)(Abt + ((size_t)b*TT + t0 + wm*64 + m*16 + row)*FF + f0 + wn*64 + c4) = vv;
      }
    }
    asm volatile("" ::: "memory");
  }
}

// ---------------- MFMA A-scale (one-time, swapped): As = R^T @ Om ----------------
__global__ __launch_bounds__(256) void k_ascalem(
    const unsigned short* __restrict__ OmbT, const unsigned short* __restrict__ Rbt,
    unsigned short* __restrict__ As)
{
  __shared__ __align__(16) unsigned char lds[16384];
  int id = blockIdx.x;                 // 2048 = b(16) x f-tile(4) x t-tile(32)
  int b  = id >> 7;
  int f0 = ((id >> 5) & 3) * 128;
  int t0 = (id & 31) * 128;
  int tid  = threadIdx.x;
  int lane = tid & 63, wid = tid >> 6;
  int lr = lane & 15, lg = lane >> 4;
  int wm = wid >> 1, wn = wid & 1;

  f32x4 acc[4][4];
  #pragma unroll
  for (int m=0;m<4;++m)
    #pragma unroll
    for (int n=0;n<4;++n)
      #pragma unroll
      for (int i=0;i<4;++i) acc[m][n][i]=0.0f;

  int swz  = ((lg ^ (lr & 3) ^ ((lr >> 2) & 3)) << 4);
  int aoff = (wm*64 + lr)*64 + swz;
  int boff = 8192 + (wn*64 + lr)*64 + swz;
  int c0 = tid, c1 = tid + 256;
  int r0 = c0 >> 2, s0 = c0 & 3;
  int r1 = c1 >> 2, s1 = c1 & 3;
  const unsigned short* gA0 = OmbT + ((size_t)b*TT + t0 + r0)*EE + ssw(r0,s0);
  const unsigned short* gA1 = OmbT + ((size_t)b*TT + t0 + r1)*EE + ssw(r1,s1);
  const unsigned short* gB0 = Rbt  + ((size_t)(b*FF + f0 + r0))*EE + ssw(r0,s0);
  const unsigned short* gB1 = Rbt  + ((size_t)(b*FF + f0 + r1))*EE + ssw(r1,s1);
  unsigned char* lA0 = lds + c0*16;
  unsigned char* lA1 = lds + c1*16;
  unsigned char* lB0 = lds + 8192 + c0*16;
  unsigned char* lB1 = lds + 8192 + c1*16;

  for (int kk=0; kk<8; ++kk){
    __syncthreads();
    int eoff = kk*32;
    gld16(gA0 + eoff, lA0);
    gld16(gA1 + eoff, lA1);
    gld16(gB0 + eoff, lB0);
    gld16(gB1 + eoff, lB1);
    asm volatile("s_waitcnt vmcnt(0)" ::: "memory");
    __syncthreads();
    bf16x8 af[4], bb[4];
    #pragma unroll
    for (int m=0;m<4;++m) af[m] = *(const bf16x8*)(lds + aoff + m*1024);
    #pragma unroll
    for (int n=0;n<4;++n) bb[n] = *(const bf16x8*)(lds + boff + n*1024);
    #pragma unroll
    for (int m=0;m<4;++m)
      #pragma unroll
      for (int n=0;n<4;++n)
        acc[m][n] = __builtin_amdgcn_mfma_f32_16x16x32_bf16(af[m], bb[n], acc[m][n], 0, 0, 0);
  }

  #pragma unroll
  for (int m=0;m<4;++m){
    int tq = wm*64 + m*16 + lg*4;
    #pragma unroll
    for (int n=0;n<4;++n){
      int floc = wn*64 + n*16 + lr;
      size_t off = ((size_t)(b*FF + f0 + floc))*TT + t0 + tq;
      ushort4 o;
      o.x = f2bf(acc[m][n][0]); o.y = f2bf(acc[m][n][1]);
      o.z = f2bf(acc[m][n][2]); o.w = f2bf(acc[m][n][3]);
      *(ushort4*)(As + off) = o;       // integer counts <=256, exact in bf16
    }
  }
}

// ---------------- launch ----------------

extern "C" void kernel_launch(void* const* d_in, const int* in_sizes, int n_in,
                              void* d_out, int out_size, void* d_ws, size_t ws_size,
                              hipStream_t stream){
  const float* Y   = (const float*)d_in[0];
  const float* Rm  = (const float*)d_in[1];
  const float* Om  = (const float*)d_in[2];
  const float* P0  = (const float*)d_in[3];
  const float* Q0  = (const float*)d_in[4];
  const float* lam = (const float*)d_in[5];
  const float* mu  = (const float*)d_in[6];
  const float* nu  = (const float*)d_in[7];
  const float* gl  = (const float*)d_in[8];
  float* A = (float*)d_out;

  char* ws = (char*)d_ws;
  const size_t X_OFF    = 0;
  const size_t REST_OFF = X_OFF    + (size_t)BB*EE*TT*4;   // X: 64 MiB
  const size_t OMB_OFF  = REST_OFF + (size_t)BB*TT*EE*2;   // residT bf16 [t][e]: 32 MiB
  const size_t AS_OFF   = OMB_OFF  + (size_t)BB*EE*TT*2;   // Omb bf16: 32 MiB
  const size_t QT_OFF   = AS_OFF   + (size_t)BB*FF*TT*2;   // As bf16: 64 MiB
  const size_t P_OFF    = QT_OFF   + (size_t)BB*RK*TT*4;
  const size_t LHS_OFF  = P_OFF    + (size_t)BB*EE*RK*4;
  const size_t INV_OFF  = LHS_OFF  + (size_t)BB*RK*RK*4;
  const size_t PRM_OFF  = INV_OFF  + (size_t)BB*RK*RK*4;
  const size_t RB_OFF   = PRM_OFF  + 4096;                 // Rb bf16 [e][f]: 4 MiB
  const size_t RBT_OFF  = RB_OFF   + (size_t)BB*EE*FF*2;   // Rbt bf16 [f][e]: 4 MiB
  const size_t OMBT_OFF = RBT_OFF  + (size_t)BB*FF*EE*2;   // OmbT bf16 [t][e]: 32 MiB
  const size_t ABT_OFF  = OMBT_OFF + (size_t)BB*TT*EE*2;   // Abt bf16 [t][f]: 64 MiB

  float* X    = (float*)(ws + X_OFF);
  unsigned short* residT = (unsigned short*)(ws + REST_OFF);
  unsigned short* Omb    = (unsigned short*)(ws + OMB_OFF);
  unsigned short* As     = (unsigned short*)(ws + AS_OFF);
  float* Qt   = (float*)(ws + QT_OFF);
  float* P    = (float*)(ws + P_OFF);
  float* lhs  = (float*)(ws + LHS_OFF);
  float* inv  = (float*)(ws + INV_OFF);
  float* prm  = (float*)(ws + PRM_OFF);
  unsigned short* Rb   = (unsigned short*)(ws + RB_OFF);
  unsigned short* Rbt  = (unsigned short*)(ws + RBT_OFF);
  unsigned short* OmbT = (unsigned short*)(ws + OMBT_OFF);
  unsigned short* Abt  = (unsigned short*)(ws + ABT_OFF);

  (void)P0; (void)Om; (void)in_sizes; (void)n_in; (void)ws_size;

  hipMemsetAsync(d_out, 0, (size_t)out_size*sizeof(float), stream);
  k_params<<<1, 64, 0, stream>>>(lam, mu, nu, gl, prm);
  k_initX<<<BB*EE*TT/4/256, 256, 0, stream>>>((const float4*)Y, (const float4*)Om,
                                              (float4*)X, (ushort4*)Omb);
  k_qtrans<<<BB*TT/256, 256, 0, stream>>>(Q0, Qt);
  k_rbf<<<BB*EE*FF/4/256, 256, 0, stream>>>((const float4*)Rm, (ushort4*)Rb);
  k_rtransb<<<dim3(FF, BB), 256, 0, stream>>>(Rm, Rbt);
  k_omtrans<<<dim3(TT/64, EE/64, BB), 256, 0, stream>>>(Omb, OmbT);
  k_ascalem<<<2048, 256, 0, stream>>>(OmbT, Rbt, As);

  for (int k=0; k<NIT; ++k){
    k_lhsQ  <<<dim3(55, BB), 256, 0, stream>>>(Qt, prm, lhs, k);
    k_invert<<<BB, 256, 0, stream>>>(lhs, inv);
    k_Pupd  <<<dim3(EE, BB), 256, 0, stream>>>(X, Qt, inv, P);
    k_lhsP  <<<dim3(55, BB), 256, 0, stream>>>(P, prm, lhs, k);
    k_invert<<<BB, 256, 0, stream>>>(lhs, inv);
    k_Qupd  <<<dim3(TT/256, BB), 256, 0, stream>>>(X, P, inv, Qt);
    k_gemm1m<<<BB*2*32, 256, 0, stream>>>(Abt, Rb, Y, Omb, Qt, P, prm, X, residT, k);
    k_gemm2m<<<2048, 256, 0, stream>>>(residT, Rbt, As, prm, A, Abt, k);
  }
}